// Round 1
// baseline (3255.287 us; speedup 1.0000x reference)
//
#include <hip/hip_runtime.h>
#include <hip/hip_bf16.h>
#include <stdint.h>

typedef __attribute__((ext_vector_type(8))) short short8;
typedef __attribute__((ext_vector_type(4))) float f32x4;

#define B_ 32
#define N_ 196
#define D_ 1024
#define V_ 32000
#define NSTEP 99
#define MROWS 3168   // 99*32
#define MPAD  3200

// workspace layout (bytes)
#define OFF_WT    0ULL          // bf16 [32000][1024]  = 65,536,000 B
#define OFF_H     65536000ULL   // bf16 [3200][1024]   =  6,553,600 B
#define OFF_FSUM  72089600ULL   // f32  [32][1024]
#define OFF_CTX   72220672ULL   // f32  [32][1024]
#define OFF_GBASE 72351744ULL   // f32  [32][4096]
#define OFF_CNT   72876032ULL   // u32 barrier counter

// ---------------- out[0] one-hot + zero H pad rows ----------------
__global__ void k_first(float* __restrict__ out, __hip_bfloat16* __restrict__ H) {
  int idx = blockIdx.x * 256 + threadIdx.x;           // 0 .. 1,024,000
  if (idx < B_ * V_) out[idx] = ((idx % V_) == 0) ? 1.0f : 0.0f;
  if (idx < 16384) ((uint32_t*)(H + (size_t)MROWS * D_))[idx] = 0u;  // rows 3168..3199
}

// ---------------- fsum[b,e] = sum_n relu(features[b,n,e]) ----------------
__global__ void k_fsum(const float* __restrict__ feat, float* __restrict__ fsum) {
  int idx = blockIdx.x * 256 + threadIdx.x;           // 32768
  int b = idx >> 10, e = idx & 1023;
  const float* p = feat + (size_t)b * (N_ * D_) + e;
  float s = 0.f;
  #pragma unroll 4
  for (int n = 0; n < N_; ++n) s += fmaxf(p[(size_t)n * D_], 0.f);
  fsum[idx] = s;
}

// ---------------- ctx[b,d] = fsum[b,:] @ W_fv[:,d] + 196*b_fv[d] ----------------
__global__ void k_ctx(const float* __restrict__ fsum, const float* __restrict__ W_fv,
                      const float* __restrict__ b_fv, float* __restrict__ ctx) {
  __shared__ float fs[1024];
  int b = blockIdx.y;
  int d = blockIdx.x * 256 + threadIdx.x;             // grid.x = 4
  for (int i = threadIdx.x; i < 1024; i += 256) fs[i] = fsum[b * 1024 + i];
  __syncthreads();
  float s = 196.f * b_fv[d];
  #pragma unroll 4
  for (int e = 0; e < 1024; ++e) s = fmaf(fs[e], W_fv[(size_t)e * 1024 + d], s);
  ctx[b * 1024 + d] = s;
}

// ---------------- gbase[b,j] = ctx[b,:] @ W_ih[:,j] + b_ih[j] + b_hh[j] ----------------
__global__ void k_gbase(const float* __restrict__ ctx, const float* __restrict__ W_ih,
                        const float* __restrict__ b_ih, const float* __restrict__ b_hh,
                        float* __restrict__ gbase) {
  __shared__ float cs[8][1024];
  int j = blockIdx.x * 256 + threadIdx.x;             // grid.x = 16 -> 0..4095
  int b0 = blockIdx.y * 8;                            // grid.y = 4
  for (int i = threadIdx.x; i < 8 * 1024; i += 256)
    cs[i >> 10][i & 1023] = ctx[(size_t)(b0 + (i >> 10)) * 1024 + (i & 1023)];
  __syncthreads();
  float bias = b_ih[j] + b_hh[j];
  float acc[8];
  #pragma unroll
  for (int r = 0; r < 8; ++r) acc[r] = bias;
  for (int e = 0; e < 1024; ++e) {
    float w = W_ih[(size_t)e * 4096 + j];
    #pragma unroll
    for (int r = 0; r < 8; ++r) acc[r] = fmaf(cs[r][e], w, acc[r]);
  }
  #pragma unroll
  for (int r = 0; r < 8; ++r) gbase[(size_t)(b0 + r) * 4096 + j] = acc[r];
}

// ---------------- W_lm [1024][32000] f32 -> WT [32000][1024] bf16 ----------------
__global__ void k_convT(const float* __restrict__ W, __hip_bfloat16* __restrict__ WT) {
  __shared__ __hip_bfloat16 t[64][66];
  int k0 = blockIdx.x * 64;                           // grid.x = 16
  int n0 = blockIdx.y * 64;                           // grid.y = 500
  int tx = threadIdx.x & 63, ty = threadIdx.x >> 6;   // 256 threads
  #pragma unroll
  for (int i = 0; i < 16; ++i) {
    int r = i * 4 + ty;
    t[r][tx] = __float2bfloat16(W[(size_t)(k0 + r) * V_ + n0 + tx]);
  }
  __syncthreads();
  #pragma unroll
  for (int i = 0; i < 16; ++i) {
    int n = i * 4 + ty;
    WT[(size_t)(n0 + n) * 1024 + k0 + tx] = t[tx][n];
  }
}

// ---------------- persistent LSTM recurrence: 128 blocks x 8 dims, 99 steps ----------------
__global__ __launch_bounds__(256, 1) void k_rec(
    const float* __restrict__ gbase, const float* __restrict__ W_hh,
    const float* __restrict__ bos, __hip_bfloat16* __restrict__ H,
    unsigned int* __restrict__ counter) {
  extern __shared__ char lds[];
  __hip_bfloat16* hbuf = (__hip_bfloat16*)lds;             // [32][1024] bf16 swizzled (64KB)
  __hip_bfloat16* wbuf = (__hip_bfloat16*)(lds + 65536);   // [32cols][1024] bf16 swizzled (64KB)
  float* gex = (float*)lds;                                // [32][33] f32, aliased on hbuf

  const int tid = threadIdx.x;
  const int blk = blockIdx.x;      // 0..127
  const int d0 = blk * 8;

  // preload W_hh slice (cols: gate g in [0,4), local dim in [0,8)) -> bf16, swizzled
  for (int idx = tid; idx < 32 * 1024; idx += 256) {
    int c = idx & 31;
    int k = idx >> 5;
    int gcol = ((c >> 3) << 10) + d0 + (c & 7);
    float w = W_hh[(size_t)k * 4096 + gcol];
    int off = c * 1024 + ((((k >> 3) ^ (c & 7)) << 3) | (k & 7));
    wbuf[off] = __float2bfloat16(w);
  }
  // h0 = bos broadcast to all batches
  for (int idx = tid; idx < 32 * 1024; idx += 256) {
    int row = idx >> 10;
    int k = idx & 1023;
    int off = row * 1024 + ((((k >> 3) ^ (row & 7)) << 3) | (k & 7));
    hbuf[off] = __float2bfloat16(bos[k]);
  }

  const int tb = tid >> 3;     // batch 0..31
  const int tdl = tid & 7;     // local dim 0..7
  float gb0 = gbase[(size_t)tb * 4096 + 0 * 1024 + d0 + tdl];
  float gb1 = gbase[(size_t)tb * 4096 + 1 * 1024 + d0 + tdl];
  float gb2 = gbase[(size_t)tb * 4096 + 2 * 1024 + d0 + tdl];
  float gb3 = gbase[(size_t)tb * 4096 + 3 * 1024 + d0 + tdl];
  float cst = 0.f;

  const int lane = tid & 63;
  const int wid = tid >> 6;
  const int wm = wid & 1;                 // M(batch) tile
  const int wn = wid >> 1;                // N(col) tile
  const int arow = wm * 16 + (lane & 15);
  const int bcol = wn * 16 + (lane & 15);
  const int kg = lane >> 4;

  __syncthreads();

  for (int t = 0; t < NSTEP; ++t) {
    // gates_local[32b x 32c] = h @ Wslice  (MFMA 16x16x32 bf16)
    f32x4 acc0 = {0.f, 0.f, 0.f, 0.f};
    f32x4 acc1 = {0.f, 0.f, 0.f, 0.f};
    #pragma unroll
    for (int kt = 0; kt < 32; kt += 2) {
      int ca = kt * 4 + kg;
      int cb = ca + 4;
      short8 a0 = *(const short8*)&hbuf[arow * 1024 + ((ca ^ (arow & 7)) << 3)];
      short8 b0 = *(const short8*)&wbuf[bcol * 1024 + ((ca ^ (bcol & 7)) << 3)];
      acc0 = __builtin_amdgcn_mfma_f32_16x16x32_bf16(a0, b0, acc0, 0, 0, 0);
      short8 a1 = *(const short8*)&hbuf[arow * 1024 + ((cb ^ (arow & 7)) << 3)];
      short8 b1 = *(const short8*)&wbuf[bcol * 1024 + ((cb ^ (bcol & 7)) << 3)];
      acc1 = __builtin_amdgcn_mfma_f32_16x16x32_bf16(a1, b1, acc1, 0, 0, 0);
    }
    acc0 = acc0 + acc1;
    __syncthreads();   // hbuf reads done -> safe to alias gex
    {
      int bq = wm * 16 + ((lane >> 4) << 2);
      #pragma unroll
      for (int q = 0; q < 4; ++q) gex[(bq + q) * 33 + bcol] = acc0[q];
    }
    __syncthreads();

    float gi = gex[tb * 33 + 0  + tdl] + gb0;
    float gf = gex[tb * 33 + 8  + tdl] + gb1;
    float gg = gex[tb * 33 + 16 + tdl] + gb2;
    float go = gex[tb * 33 + 24 + tdl] + gb3;
    float si = 1.f / (1.f + __expf(-gi));
    float sf = 1.f / (1.f + __expf(-gf));
    float so = 1.f / (1.f + __expf(-go));
    cst = sf * cst + si * tanhf(gg);
    float h = so * tanhf(cst);
    H[(size_t)t * (B_ * D_) + tb * D_ + d0 + tdl] = __float2bfloat16(h);

    if (t == NSTEP - 1) break;

    // device-wide barrier (all 128 blocks co-resident: 1 block/CU, 128 <= 256 CUs)
    __threadfence();
    __syncthreads();
    if (tid == 0) {
      atomicAdd(counter, 1u);
      unsigned target = (unsigned)(128 * (t + 1));
      while (__hip_atomic_load(counter, __ATOMIC_ACQUIRE, __HIP_MEMORY_SCOPE_AGENT) < target)
        __builtin_amdgcn_s_sleep(1);
    }
    __syncthreads();
    __threadfence();   // acquire: see other blocks' H writes

    // restage h(t) from global into hbuf (swizzled)
    const uint4* src = (const uint4*)(H + (size_t)t * (B_ * D_));  // 4096 x 16B chunks
    for (int i = tid; i < 4096; i += 256) {
      uint4 v = src[i];
      int row = i >> 7;
      int ch = i & 127;
      int sw = ch ^ (row & 7);
      *(uint4*)&hbuf[row * 1024 + sw * 8] = v;
    }
    __syncthreads();
  }
}

// ---------------- logits GEMM: [3200,1024] x [1024,32000] bf16 MFMA, 128x128 tiles ----------------
__global__ __launch_bounds__(256, 2) void k_gemm(
    const __hip_bfloat16* __restrict__ H,    // [3200][1024]
    const __hip_bfloat16* __restrict__ WT,   // [32000][1024]
    const float* __restrict__ b_lm,
    float* __restrict__ out) {
  __shared__ __hip_bfloat16 As[128 * 72];    // 128 rows x (64 + 8 pad) bf16
  __shared__ __hip_bfloat16 Bs[128 * 72];

  // bijective XCD swizzle: nwg = 6250 = 8*781 + 2
  int bid = blockIdx.x;
  int xcd = bid & 7;
  int idx = bid >> 3;
  int wg = (xcd < 2 ? xcd * 782 : 2 * 782 + (xcd - 2) * 781) + idx;
  int mt = wg % 25;          // m fastest: 25 blocks share one B panel (L2 reuse)
  int nt = wg / 25;
  const size_t mbase = (size_t)mt * 128;
  const size_t nbase = (size_t)nt * 128;

  const int tid = threadIdx.x;
  const int lane = tid & 63;
  const int wid = tid >> 6;
  const int wh = wid >> 1;      // M half
  const int ww = wid & 1;       // N half

  f32x4 acc[4][4];
  #pragma unroll
  for (int m = 0; m < 4; ++m)
    #pragma unroll
    for (int n = 0; n < 4; ++n) acc[m][n] = (f32x4){0.f, 0.f, 0.f, 0.f};

  const int arow = wh * 64 + (lane & 15);
  const int brow = ww * 64 + (lane & 15);
  const int kg = lane >> 4;

  for (int kt = 0; kt < 16; ++kt) {          // BK = 64
    __syncthreads();
    #pragma unroll
    for (int j = 0; j < 4; ++j) {            // stage A: 1024 chunks of 16B
      int cidx = tid + j * 256;
      int row = cidx >> 3;
      int ch = cidx & 7;
      uint4 va = *(const uint4*)&H[(mbase + row) * 1024 + kt * 64 + ch * 8];
      *(uint4*)&As[row * 72 + ch * 8] = va;
    }
    #pragma unroll
    for (int j = 0; j < 4; ++j) {            // stage B
      int cidx = tid + j * 256;
      int row = cidx >> 3;
      int ch = cidx & 7;
      uint4 vb = *(const uint4*)&WT[(nbase + row) * 1024 + kt * 64 + ch * 8];
      *(uint4*)&Bs[row * 72 + ch * 8] = vb;
    }
    __syncthreads();
    #pragma unroll
    for (int kk = 0; kk < 2; ++kk) {
      short8 a[4], b[4];
      #pragma unroll
      for (int m = 0; m < 4; ++m)
        a[m] = *(const short8*)&As[(arow + m * 16) * 72 + kk * 32 + kg * 8];
      #pragma unroll
      for (int n = 0; n < 4; ++n)
        b[n] = *(const short8*)&Bs[(brow + n * 16) * 72 + kk * 32 + kg * 8];
      #pragma unroll
      for (int m = 0; m < 4; ++m)
        #pragma unroll
        for (int n = 0; n < 4; ++n)
          acc[m][n] = __builtin_amdgcn_mfma_f32_16x16x32_bf16(a[m], b[n], acc[m][n], 0, 0, 0);
    }
  }

  #pragma unroll
  for (int n = 0; n < 4; ++n) {
    int gcol = (int)nbase + ww * 64 + n * 16 + (lane & 15);
    float bl = b_lm[gcol];
    #pragma unroll
    for (int m = 0; m < 4; ++m) {
      int rbase = (int)mbase + wh * 64 + m * 16 + ((lane >> 4) << 2);
      #pragma unroll
      for (int q = 0; q < 4; ++q) {
        int r = rbase + q;
        if (r < MROWS)
          out[(size_t)(r + 32) * V_ + gcol] = acc[m][n][q] + bl;
      }
    }
  }
}

extern "C" void kernel_launch(void* const* d_in, const int* in_sizes, int n_in,
                              void* d_out, int out_size, void* d_ws, size_t ws_size,
                              hipStream_t stream) {
  const float* features = (const float*)d_in[0];
  // d_in[1]=W_fk, d_in[2]=b_fk, d_in[5]=W_tk, d_in[6]=b_tk : dead code (softmax over size-1 axis)
  const float* W_fv = (const float*)d_in[3];
  const float* b_fv = (const float*)d_in[4];
  const float* W_ih = (const float*)d_in[7];
  const float* W_hh = (const float*)d_in[8];
  const float* b_ih = (const float*)d_in[9];
  const float* b_hh = (const float*)d_in[10];
  const float* W_lm = (const float*)d_in[11];
  const float* b_lm = (const float*)d_in[12];
  const float* bos  = (const float*)d_in[13];
  float* out = (float*)d_out;
  char* ws = (char*)d_ws;

  __hip_bfloat16* WT   = (__hip_bfloat16*)(ws + OFF_WT);
  __hip_bfloat16* H    = (__hip_bfloat16*)(ws + OFF_H);
  float* fsum          = (float*)(ws + OFF_FSUM);
  float* ctx           = (float*)(ws + OFF_CTX);
  float* gbase         = (float*)(ws + OFF_GBASE);
  unsigned int* cnt    = (unsigned int*)(ws + OFF_CNT);

  hipMemsetAsync(cnt, 0, 4, stream);
  hipLaunchKernelGGL(k_first, dim3(4000), dim3(256), 0, stream, out, H);
  hipLaunchKernelGGL(k_fsum,  dim3(128),  dim3(256), 0, stream, features, fsum);
  hipLaunchKernelGGL(k_ctx,   dim3(4, 32),  dim3(256), 0, stream, fsum, W_fv, b_fv, ctx);
  hipLaunchKernelGGL(k_gbase, dim3(16, 4),  dim3(256), 0, stream, ctx, W_ih, b_ih, b_hh, gbase);
  hipLaunchKernelGGL(k_convT, dim3(16, 500), dim3(256), 0, stream, W_lm, WT);
  hipLaunchKernelGGL(k_rec,   dim3(128),  dim3(256), 131072, stream, gbase, W_hh, bos, H, cnt);
  hipLaunchKernelGGL(k_gemm,  dim3(6250), dim3(256), 0, stream, H, WT, b_lm, out);
}

// Round 2
// 1297.943 us; speedup vs baseline: 2.5080x; 2.5080x over previous
//
#include <hip/hip_runtime.h>
#include <hip/hip_bf16.h>
#include <stdint.h>

typedef __attribute__((ext_vector_type(8))) short short8;
typedef __attribute__((ext_vector_type(4))) float f32x4;

#define B_ 32
#define N_ 196
#define D_ 1024
#define V_ 32000
#define NSTEP 99
#define MROWS 3168   // 99*32
#define MPAD  3200

// workspace layout (bytes)
#define OFF_WT    0ULL          // bf16 [32000][1024]  = 65,536,000 B
#define OFF_H     65536000ULL   // bf16 [3200][1024]   =  6,553,600 B
#define OFF_FSUM  72089600ULL   // f32  [32][1024]     (dead after k_gbase)
#define OFF_CTX   72220672ULL   // f32  [32][1024]     (dead after k_gbase)
#define OFF_EX    72089600ULL   // u64  [2][128][128]  = 262,144 B (aliases FSUM+CTX)
#define OFF_GBASE 72351744ULL   // f32  [32][4096]

// ---------------- out[0] one-hot + zero H pad rows ----------------
__global__ void k_first(float* __restrict__ out, __hip_bfloat16* __restrict__ H) {
  int idx = blockIdx.x * 256 + threadIdx.x;           // 0 .. 1,024,000
  if (idx < B_ * V_) out[idx] = ((idx % V_) == 0) ? 1.0f : 0.0f;
  if (idx < 16384) ((uint32_t*)(H + (size_t)MROWS * D_))[idx] = 0u;  // rows 3168..3199
}

// ---------------- fsum[b,e] = sum_n relu(features[b,n,e]) ----------------
__global__ void k_fsum(const float* __restrict__ feat, float* __restrict__ fsum) {
  int idx = blockIdx.x * 256 + threadIdx.x;           // 32768
  int b = idx >> 10, e = idx & 1023;
  const float* p = feat + (size_t)b * (N_ * D_) + e;
  float s = 0.f;
  #pragma unroll 4
  for (int n = 0; n < N_; ++n) s += fmaxf(p[(size_t)n * D_], 0.f);
  fsum[idx] = s;
}

// ---------------- ctx[b,d] = fsum[b,:] @ W_fv[:,d] + 196*b_fv[d] ----------------
__global__ void k_ctx(const float* __restrict__ fsum, const float* __restrict__ W_fv,
                      const float* __restrict__ b_fv, float* __restrict__ ctx) {
  __shared__ float fs[1024];
  int b = blockIdx.y;
  int d = blockIdx.x * 256 + threadIdx.x;             // grid.x = 4
  for (int i = threadIdx.x; i < 1024; i += 256) fs[i] = fsum[b * 1024 + i];
  __syncthreads();
  float s = 196.f * b_fv[d];
  #pragma unroll 4
  for (int e = 0; e < 1024; ++e) s = fmaf(fs[e], W_fv[(size_t)e * 1024 + d], s);
  ctx[b * 1024 + d] = s;
}

// ---------------- gbase[b,j] = ctx[b,:] @ W_ih[:,j] + b_ih[j] + b_hh[j] ----------------
__global__ void k_gbase(const float* __restrict__ ctx, const float* __restrict__ W_ih,
                        const float* __restrict__ b_ih, const float* __restrict__ b_hh,
                        float* __restrict__ gbase) {
  __shared__ float cs[8][1024];
  int j = blockIdx.x * 256 + threadIdx.x;             // grid.x = 16 -> 0..4095
  int b0 = blockIdx.y * 8;                            // grid.y = 4
  for (int i = threadIdx.x; i < 8 * 1024; i += 256)
    cs[i >> 10][i & 1023] = ctx[(size_t)(b0 + (i >> 10)) * 1024 + (i & 1023)];
  __syncthreads();
  float bias = b_ih[j] + b_hh[j];
  float acc[8];
  #pragma unroll
  for (int r = 0; r < 8; ++r) acc[r] = bias;
  for (int e = 0; e < 1024; ++e) {
    float w = W_ih[(size_t)e * 4096 + j];
    #pragma unroll
    for (int r = 0; r < 8; ++r) acc[r] = fmaf(cs[r][e], w, acc[r]);
  }
  #pragma unroll
  for (int r = 0; r < 8; ++r) gbase[(size_t)(b0 + r) * 4096 + j] = acc[r];
}

// ---------------- W_lm [1024][32000] f32 -> WT [32000][1024] bf16 ----------------
__global__ void k_convT(const float* __restrict__ W, __hip_bfloat16* __restrict__ WT) {
  __shared__ __hip_bfloat16 t[64][66];
  int k0 = blockIdx.x * 64;                           // grid.x = 16
  int n0 = blockIdx.y * 64;                           // grid.y = 500
  int tx = threadIdx.x & 63, ty = threadIdx.x >> 6;   // 256 threads
  #pragma unroll
  for (int i = 0; i < 16; ++i) {
    int r = i * 4 + ty;
    t[r][tx] = __float2bfloat16(W[(size_t)(k0 + r) * V_ + n0 + tx]);
  }
  __syncthreads();
  #pragma unroll
  for (int i = 0; i < 16; ++i) {
    int n = i * 4 + ty;
    WT[(size_t)(n0 + n) * 1024 + k0 + tx] = t[tx][n];
  }
}

// ---------------- persistent LSTM recurrence: 128 blocks x 8 dims, 99 steps ----------------
// Fence-free exchange: each h-pair published as one u64 relaxed AGENT atomic word
// (tag = t+1 in high dword, 2x bf16 payload in low dword). Parity double-buffer.
__global__ __launch_bounds__(256, 1) void k_rec(
    const float* __restrict__ gbase, const float* __restrict__ W_hh,
    const float* __restrict__ bos, __hip_bfloat16* __restrict__ H,
    unsigned long long* __restrict__ Ex) {
  extern __shared__ char lds[];
  __hip_bfloat16* hbuf = (__hip_bfloat16*)lds;             // [32][1024] bf16 swizzled (64KB)
  __hip_bfloat16* wbuf = (__hip_bfloat16*)(lds + 65536);   // [32cols][1024] bf16 swizzled (64KB, init only)
  float* gex = (float*)(lds + 131072);                     // [32][33] f32 (4.2KB)

  const int tid = threadIdx.x;
  const int blk = blockIdx.x;      // 0..127
  const int d0 = blk * 8;

  // preload W_hh slice (cols: gate g in [0,4), local dim in [0,8)) -> bf16, swizzled
  for (int idx = tid; idx < 32 * 1024; idx += 256) {
    int c = idx & 31;
    int k = idx >> 5;
    int gcol = ((c >> 3) << 10) + d0 + (c & 7);
    float w = W_hh[(size_t)k * 4096 + gcol];
    int off = c * 1024 + ((((k >> 3) ^ (c & 7)) << 3) | (k & 7));
    wbuf[off] = __float2bfloat16(w);
  }
  // h0 = bos broadcast to all batches
  for (int idx = tid; idx < 32 * 1024; idx += 256) {
    int row = idx >> 10;
    int k = idx & 1023;
    int off = row * 1024 + ((((k >> 3) ^ (row & 7)) << 3) | (k & 7));
    hbuf[off] = __float2bfloat16(bos[k]);
  }

  const int tb = tid >> 3;     // batch 0..31
  const int tdl = tid & 7;     // local dim 0..7
  float gb0 = gbase[(size_t)tb * 4096 + 0 * 1024 + d0 + tdl];
  float gb1 = gbase[(size_t)tb * 4096 + 1 * 1024 + d0 + tdl];
  float gb2 = gbase[(size_t)tb * 4096 + 2 * 1024 + d0 + tdl];
  float gb3 = gbase[(size_t)tb * 4096 + 3 * 1024 + d0 + tdl];
  float cst = 0.f;

  const int lane = tid & 63;
  const int wid = tid >> 6;
  const int wm = wid & 1;                 // M(batch) tile
  const int wn = wid >> 1;                // N(col) tile
  const int arow = wm * 16 + (lane & 15);
  const int bcol = wn * 16 + (lane & 15);
  const int kg = lane >> 4;
  const int axor = arow & 7;

  __syncthreads();

  // hoist W_hh B-fragments into registers (32 x short8 = 128 VGPR)
  short8 breg[32];
  #pragma unroll
  for (int kt = 0; kt < 32; ++kt) {
    int ca = kt * 4 + kg;
    breg[kt] = *(const short8*)&wbuf[bcol * 1024 + ((ca ^ (bcol & 7)) << 3)];
  }

  // consumer-side constants: thread handles words g = w*256 + tid
  const int cbatch = (tid >> 2) & 31;
  const int cpair = tid & 3;
  const int chi = tid >> 7;                 // 0/1
  const int cbase = cbatch * 1024 + cpair * 2;
  const int bxor = cbatch & 7;

  for (int t = 0; t < NSTEP; ++t) {
    // gates_local[32b x 32c] = h @ Wslice  (MFMA 16x16x32 bf16, B in regs)
    f32x4 acc0 = {0.f, 0.f, 0.f, 0.f};
    f32x4 acc1 = {0.f, 0.f, 0.f, 0.f};
    #pragma unroll
    for (int kt = 0; kt < 32; kt += 2) {
      int ca = kt * 4 + kg;
      short8 a0 = *(const short8*)&hbuf[arow * 1024 + ((ca ^ axor) << 3)];
      acc0 = __builtin_amdgcn_mfma_f32_16x16x32_bf16(a0, breg[kt], acc0, 0, 0, 0);
      short8 a1 = *(const short8*)&hbuf[arow * 1024 + (((ca + 4) ^ axor) << 3)];
      acc1 = __builtin_amdgcn_mfma_f32_16x16x32_bf16(a1, breg[kt + 1], acc1, 0, 0, 0);
    }
    acc0 = acc0 + acc1;
    {
      int bq = wm * 16 + ((lane >> 4) << 2);
      #pragma unroll
      for (int q = 0; q < 4; ++q) gex[(bq + q) * 33 + bcol] = acc0[q];
    }
    __syncthreads();   // S1: gex written

    float gi = gex[tb * 33 + 0  + tdl] + gb0;
    float gf = gex[tb * 33 + 8  + tdl] + gb1;
    float gg = gex[tb * 33 + 16 + tdl] + gb2;
    float go = gex[tb * 33 + 24 + tdl] + gb3;
    float si = 1.f / (1.f + __expf(-gi));
    float sf = 1.f / (1.f + __expf(-gf));
    float so = 1.f / (1.f + __expf(-go));
    cst = sf * cst + si * tanhf(gg);
    float h = so * tanhf(cst);
    H[(size_t)t * (B_ * D_) + tb * D_ + d0 + tdl] = __float2bfloat16(h);

    // publish h-pair as tagged u64 (fence-free, relaxed agent atomic)
    float hother = __shfl_xor(h, 1);
    if ((tdl & 1) == 0) {
      __hip_bfloat16 b0 = __float2bfloat16(h);
      __hip_bfloat16 b1 = __float2bfloat16(hother);
      uint32_t pk = (uint32_t)*(uint16_t*)&b0 | ((uint32_t)*(uint16_t*)&b1 << 16);
      unsigned long long v = ((unsigned long long)(unsigned)(t + 1) << 32) | pk;
      unsigned long long* dst = Ex + ((t & 1) ? 16384 : 0) + blk * 128 + tb * 4 + (tdl >> 1);
      __hip_atomic_store(dst, v, __ATOMIC_RELAXED, __HIP_MEMORY_SCOPE_AGENT);
    }

    if (t == NSTEP - 1) break;

    // poll all 16384 words (64/thread), idempotent deposit into hbuf
    {
      const unsigned long long want = (unsigned long long)(unsigned)(t + 1);
      const unsigned long long* ExB = Ex + ((t & 1) ? 16384 : 0);
      for (;;) {
        int nready = 0;
        #pragma unroll
        for (int half = 0; half < 2; ++half) {
          unsigned long long v[32];
          #pragma unroll
          for (int j = 0; j < 32; ++j)
            v[j] = __hip_atomic_load(&ExB[(half * 32 + j) * 256 + tid],
                                     __ATOMIC_RELAXED, __HIP_MEMORY_SCOPE_AGENT);
          #pragma unroll
          for (int j = 0; j < 32; ++j) {
            if ((v[j] >> 32) == want) {
              int slice = (half * 32 + j) * 2 + chi;
              *(uint32_t*)&hbuf[cbase + ((slice ^ bxor) << 3)] = (uint32_t)v[j];
              ++nready;
            }
          }
        }
        if (nready == 64) break;
        __builtin_amdgcn_s_sleep(1);
      }
    }
    __syncthreads();   // S2: hbuf fully deposited
  }
}

// ---------------- logits GEMM: [3200,1024] x [1024,32000] bf16 MFMA, 128x128 tiles ----------------
__global__ __launch_bounds__(256, 2) void k_gemm(
    const __hip_bfloat16* __restrict__ H,    // [3200][1024]
    const __hip_bfloat16* __restrict__ WT,   // [32000][1024]
    const float* __restrict__ b_lm,
    float* __restrict__ out) {
  __shared__ __hip_bfloat16 As[128 * 72];    // 128 rows x (64 + 8 pad) bf16
  __shared__ __hip_bfloat16 Bs[128 * 72];

  // bijective XCD swizzle: nwg = 6250 = 8*781 + 2
  int bid = blockIdx.x;
  int xcd = bid & 7;
  int idx = bid >> 3;
  int wg = (xcd < 2 ? xcd * 782 : 2 * 782 + (xcd - 2) * 781) + idx;
  int mt = wg % 25;          // m fastest: 25 blocks share one B panel (L2 reuse)
  int nt = wg / 25;
  const size_t mbase = (size_t)mt * 128;
  const size_t nbase = (size_t)nt * 128;

  const int tid = threadIdx.x;
  const int lane = tid & 63;
  const int wid = tid >> 6;
  const int wh = wid >> 1;      // M half
  const int ww = wid & 1;       // N half

  f32x4 acc[4][4];
  #pragma unroll
  for (int m = 0; m < 4; ++m)
    #pragma unroll
    for (int n = 0; n < 4; ++n) acc[m][n] = (f32x4){0.f, 0.f, 0.f, 0.f};

  const int arow = wh * 64 + (lane & 15);
  const int brow = ww * 64 + (lane & 15);
  const int kg = lane >> 4;

  for (int kt = 0; kt < 16; ++kt) {          // BK = 64
    __syncthreads();
    #pragma unroll
    for (int j = 0; j < 4; ++j) {            // stage A: 1024 chunks of 16B
      int cidx = tid + j * 256;
      int row = cidx >> 3;
      int ch = cidx & 7;
      uint4 va = *(const uint4*)&H[(mbase + row) * 1024 + kt * 64 + ch * 8];
      *(uint4*)&As[row * 72 + ch * 8] = va;
    }
    #pragma unroll
    for (int j = 0; j < 4; ++j) {            // stage B
      int cidx = tid + j * 256;
      int row = cidx >> 3;
      int ch = cidx & 7;
      uint4 vb = *(const uint4*)&WT[(nbase + row) * 1024 + kt * 64 + ch * 8];
      *(uint4*)&Bs[row * 72 + ch * 8] = vb;
    }
    __syncthreads();
    #pragma unroll
    for (int kk = 0; kk < 2; ++kk) {
      short8 a[4], b[4];
      #pragma unroll
      for (int m = 0; m < 4; ++m)
        a[m] = *(const short8*)&As[(arow + m * 16) * 72 + kk * 32 + kg * 8];
      #pragma unroll
      for (int n = 0; n < 4; ++n)
        b[n] = *(const short8*)&Bs[(brow + n * 16) * 72 + kk * 32 + kg * 8];
      #pragma unroll
      for (int m = 0; m < 4; ++m)
        #pragma unroll
        for (int n = 0; n < 4; ++n)
          acc[m][n] = __builtin_amdgcn_mfma_f32_16x16x32_bf16(a[m], b[n], acc[m][n], 0, 0, 0);
    }
  }

  #pragma unroll
  for (int n = 0; n < 4; ++n) {
    int gcol = (int)nbase + ww * 64 + n * 16 + (lane & 15);
    float bl = b_lm[gcol];
    #pragma unroll
    for (int m = 0; m < 4; ++m) {
      int rbase = (int)mbase + wh * 64 + m * 16 + ((lane >> 4) << 2);
      #pragma unroll
      for (int q = 0; q < 4; ++q) {
        int r = rbase + q;
        if (r < MROWS)
          out[(size_t)(r + 32) * V_ + gcol] = acc[m][n][q] + bl;
      }
    }
  }
}

extern "C" void kernel_launch(void* const* d_in, const int* in_sizes, int n_in,
                              void* d_out, int out_size, void* d_ws, size_t ws_size,
                              hipStream_t stream) {
  const float* features = (const float*)d_in[0];
  // d_in[1]=W_fk, d_in[2]=b_fk, d_in[5]=W_tk, d_in[6]=b_tk : dead code (softmax over size-1 axis)
  const float* W_fv = (const float*)d_in[3];
  const float* b_fv = (const float*)d_in[4];
  const float* W_ih = (const float*)d_in[7];
  const float* W_hh = (const float*)d_in[8];
  const float* b_ih = (const float*)d_in[9];
  const float* b_hh = (const float*)d_in[10];
  const float* W_lm = (const float*)d_in[11];
  const float* b_lm = (const float*)d_in[12];
  const float* bos  = (const float*)d_in[13];
  float* out = (float*)d_out;
  char* ws = (char*)d_ws;

  __hip_bfloat16* WT   = (__hip_bfloat16*)(ws + OFF_WT);
  __hip_bfloat16* H    = (__hip_bfloat16*)(ws + OFF_H);
  float* fsum          = (float*)(ws + OFF_FSUM);
  float* ctx           = (float*)(ws + OFF_CTX);
  float* gbase         = (float*)(ws + OFF_GBASE);
  unsigned long long* Ex = (unsigned long long*)(ws + OFF_EX);

  hipLaunchKernelGGL(k_first, dim3(4000), dim3(256), 0, stream, out, H);
  hipLaunchKernelGGL(k_fsum,  dim3(128),  dim3(256), 0, stream, features, fsum);
  hipLaunchKernelGGL(k_ctx,   dim3(4, 32),  dim3(256), 0, stream, fsum, W_fv, b_fv, ctx);
  hipLaunchKernelGGL(k_gbase, dim3(16, 4),  dim3(256), 0, stream, ctx, W_ih, b_ih, b_hh, gbase);
  hipLaunchKernelGGL(k_convT, dim3(16, 500), dim3(256), 0, stream, W_lm, WT);
  // Ex aliases fsum+ctx (both dead now); zero tags before k_rec
  hipMemsetAsync(Ex, 0, 262144, stream);
  hipLaunchKernelGGL(k_rec,   dim3(128),  dim3(256), 135296, stream, gbase, W_hh, bos, H, Ex);
  hipLaunchKernelGGL(k_gemm,  dim3(6250), dim3(256), 0, stream, H, WT, b_lm, out);
}